// Round 23
// baseline (146.984 us; speedup 1.0000x reference)
//
#include <hip/hip_runtime.h>
#include <stdint.h>

#define L_SEQ 2048
#define DIM 1536
#define NH 24
#define HD 64
#define NQKV 4608

typedef unsigned short u16;
typedef __attribute__((ext_vector_type(4))) float f32x4;
typedef __attribute__((ext_vector_type(8))) short bf16x8;
typedef __attribute__((ext_vector_type(4))) u16 u16x4;
typedef __attribute__((ext_vector_type(8))) u16 u16x8;

__device__ __forceinline__ u16 f2bf(float f) {
  unsigned u = __builtin_bit_cast(unsigned, f);
  u += 0x7fffu + ((u >> 16) & 1u);
  return (u16)(u >> 16);
}
__device__ __forceinline__ float b2f(u16 u) {
  return __builtin_bit_cast(float, (unsigned)u << 16);
}
__device__ __forceinline__ unsigned cvt_pk_bf16(float lo, float hi) {
  unsigned r;
  asm("v_cvt_pk_bf16_f32 %0, %1, %2" : "=v"(r) : "v"(lo), "v"(hi));
  return r;
}

__device__ __forceinline__ void gload_lds16(const void* g, void* lds) {
  __builtin_amdgcn_global_load_lds(
      (const __attribute__((address_space(1))) unsigned int*)g,
      (__attribute__((address_space(3))) unsigned int*)lds, 16, 0, 0);
}

// ---------------- fused cast f32 -> bf16 for x, w_qkv, w_proj ----------------
__global__ __launch_bounds__(256) void cast3_kernel(const float* __restrict__ x,
                                                    const float* __restrict__ wq,
                                                    const float* __restrict__ wp,
                                                    u16* __restrict__ out) {
  const int n1 = (L_SEQ * DIM) / 4;
  const int n2 = (NQKV * DIM) / 4;
  const int n3 = (DIM * DIM) / 4;
  const int tot = n1 + n2 + n3;
  for (int i = blockIdx.x * 256 + threadIdx.x; i < tot; i += gridDim.x * 256) {
    const f32x4* src;
    int j;
    if (i < n1) {
      src = (const f32x4*)x;
      j = i;
    } else if (i < n1 + n2) {
      src = (const f32x4*)wq;
      j = i - n1;
    } else {
      src = (const f32x4*)wp;
      j = i - n1 - n2;
    }
    f32x4 v = src[j];
    u16x4 o;
    o.x = f2bf(v.x);
    o.y = f2bf(v.y);
    o.z = f2bf(v.z);
    o.w = f2bf(v.w);
    ((u16x4*)out)[i] = o;
  }
}

// ---------------- GEMM: C[M][N] = A[M][K] * B[N][K]^T + bias ----------------
// 128 x BN tile (BN=128 or 64), BK=32, 4 waves, 16x16x32 MFMA, global_load_lds,
// 2-phase dbuf, XCD-bijective swizzle. Wave = 64 rows x BN/2 cols.
template <int WRITE_BF16, int BN>
__global__ __launch_bounds__(256) void gemm_bt(const u16* __restrict__ A,
                                               const u16* __restrict__ B,
                                               const float* __restrict__ bias,
                                               void* __restrict__ Cout,
                                               int M, int N, int K) {
  constexpr int NT = BN / 64 * 2;  // acc col-frags per wave: 4 (BN=128) or 2 (BN=64)
  __shared__ u16 As[2][128 * 32];
  __shared__ u16 Bs[2][BN * 32];
  const int mb = M >> 7;
  const int f = (int)blockIdx.x;
  const int f2 = (f & 7) * ((int)gridDim.x >> 3) + (f >> 3);
  const int bx = f2 / mb;  // col tile (slow within an XCD chunk)
  const int by = f2 % mb;  // row tile (fast)
  const int tid = threadIdx.x;
  const int lane = tid & 63;
  const int l4 = lane & 15;
  const int wv = tid >> 6;
  const int wr = wv >> 1, wc = wv & 1;

  f32x4 acc[4][NT];
#pragma unroll
  for (int i = 0; i < 4; i++)
#pragma unroll
    for (int j = 0; j < NT; j++) acc[i][j] = (f32x4)(0.0f);

  const int e0 = tid * 8;
  const int r0 = e0 >> 5, c0 = e0 & 31;
  const u16* Ag0 = A + (size_t)(by * 128 + r0) * K + c0;
  const u16* Ag1 = A + (size_t)(by * 128 + r0 + 64) * K + c0;
  const u16* Bg0 = B + (size_t)(bx * BN + r0) * K + c0;
  const u16* Bg1 = B + (size_t)(bx * BN + r0 + 64) * K + c0;  // used only BN=128
  const int kc = (lane >> 4) * 8;
  const int wb = wv * 1024;

  gload_lds16(Ag0, (char*)As[0] + wb);
  gload_lds16(Ag1, (char*)As[0] + wb + 4096);
  gload_lds16(Bg0, (char*)Bs[0] + wb);
  if (BN == 128) gload_lds16(Bg1, (char*)Bs[0] + wb + 4096);
  __syncthreads();

  int cur = 0;
  for (int k0 = 0; k0 < K; k0 += 32) {
    const int nxt = cur ^ 1;
    if (k0 + 32 < K) {
      gload_lds16(Ag0 + k0 + 32, (char*)As[nxt] + wb);
      gload_lds16(Ag1 + k0 + 32, (char*)As[nxt] + wb + 4096);
      gload_lds16(Bg0 + k0 + 32, (char*)Bs[nxt] + wb);
      if (BN == 128) gload_lds16(Bg1 + k0 + 32, (char*)Bs[nxt] + wb + 4096);
    }
    const u16* Asc = As[cur];
    const u16* Bsc = Bs[cur];
    bf16x8 af[4], bfr[NT];
#pragma unroll
    for (int mt = 0; mt < 4; mt++)
      af[mt] = *(const bf16x8*)&Asc[(wr * 64 + mt * 16 + l4) * 32 + kc];
#pragma unroll
    for (int nt = 0; nt < NT; nt++)
      bfr[nt] = *(const bf16x8*)&Bsc[(wc * (BN / 2) + nt * 16 + l4) * 32 + kc];
#pragma unroll
    for (int mt = 0; mt < 4; mt++)
#pragma unroll
      for (int nt = 0; nt < NT; nt++)
        acc[mt][nt] = __builtin_amdgcn_mfma_f32_16x16x32_bf16(af[mt], bfr[nt],
                                                              acc[mt][nt], 0, 0, 0);
    __syncthreads();
    cur = nxt;
  }

  // C/D layout: col = l4, row = (lane>>4)*4 + reg
  const int colb = bx * BN + wc * (BN / 2) + l4;
  const int rowb = by * 128 + wr * 64 + ((lane >> 4) << 2);
#pragma unroll
  for (int nt = 0; nt < NT; nt++) {
    const int col = colb + nt * 16;
    const float bv = bias[col];
#pragma unroll
    for (int mt = 0; mt < 4; mt++) {
#pragma unroll
      for (int r = 0; r < 4; r++) {
        const int row = rowb + mt * 16 + r;
        float v = acc[mt][nt][r] + bv;
        if (WRITE_BF16)
          ((u16*)Cout)[(size_t)row * N + col] = f2bf(v);
        else
          ((float*)Cout)[(size_t)row * N + col] = v;
      }
    }
  }
}

// ---------------- QK-RMSNorm + layout rearrange (bf16 qkv input) ------------
__global__ __launch_bounds__(256) void qkvnorm_kernel(const u16* __restrict__ qkv,
                                                      const float* __restrict__ gq,
                                                      const float* __restrict__ gk,
                                                      u16* __restrict__ Qh,
                                                      u16* __restrict__ Kh,
                                                      u16* __restrict__ Vt) {
  const int h = blockIdx.y;
  const int lblk = blockIdx.x * 64;
  const int tid = threadIdx.x;
  const int lane = tid & 63, wv = tid >> 6;
  __shared__ u16 vt[64][64];
  const float gqv = gq[lane] * 0.125f * 1.44269504088896f;  // 1/sqrt(HD) * log2(e)
  const float gkv = gk[lane];
#pragma unroll 1
  for (int i = 0; i < 16; i++) {
    const int l = lblk + wv * 16 + i;
    const size_t base = (size_t)l * NQKV + h * HD + lane;
    const float q = b2f(qkv[base]);
    const float k = b2f(qkv[base + DIM]);
    float sq = q * q, sk = k * k;
#pragma unroll
    for (int m = 32; m; m >>= 1) {
      sq += __shfl_xor(sq, m);
      sk += __shfl_xor(sk, m);
    }
    const float rq = rsqrtf(sq * (1.0f / 64.0f) + 1e-6f);
    const float rk = rsqrtf(sk * (1.0f / 64.0f) + 1e-6f);
    const size_t ho = ((size_t)h * L_SEQ + l) * HD + lane;
    Qh[ho] = f2bf(q * rq * gqv);
    Kh[ho] = f2bf(k * rk * gkv);
    vt[wv * 16 + i][lane] = qkv[base + 2 * DIM];
  }
  __syncthreads();
  const int d = tid >> 2;
  const int cb = (tid & 3) * 16;
  u16* dst = Vt + ((size_t)h * HD + d) * L_SEQ + lblk + cb;
#pragma unroll
  for (int j0 = 0; j0 < 4; j0++) {
    u16x4 o;
    o.x = vt[cb + j0 * 4 + 0][d];
    o.y = vt[cb + j0 * 4 + 1][d];
    o.z = vt[cb + j0 * 4 + 2][d];
    o.w = vt[cb + j0 * 4 + 3][d];
    *(u16x4*)(dst + j0 * 4) = o;
  }
}

// ---------------- MFMA flash: R21 compute + global_load_lds staging ----------
// MAX-SHIFT softmax only (fixed-shift fails 3/3 across structures — closed).
// Staging now via global_load_lds with PRE-SWIZZLED GLOBAL SOURCE (guide #21/
// m173): linear LDS dest + source col = lin_col ^ ((row&7)<<3) (involution)
// lands the byte-identical swizzled LDS image; reads unchanged. Same async
// staging pattern as the 23/23-passing gemm_bt. P-path byte-identical to R21
// incl. the compiler memory fence.
__global__ __launch_bounds__(256) void flash_kernel(const u16* __restrict__ Qh,
                                                    const u16* __restrict__ Kh,
                                                    const u16* __restrict__ Vt,
                                                    u16* __restrict__ O) {
  const int f = (int)blockIdx.y * (L_SEQ / 64) + (int)blockIdx.x;  // 0..767
  const int f2 = (f & 7) * 96 + (f >> 3);  // bijective (768 % 8 == 0)
  const int h = f2 >> 5;
  const int qblk = (f2 & 31) * 64;
  const int tid = threadIdx.x;
  const int lane = tid & 63, wv = tid >> 6;
  __shared__ u16 Ks[2 * 64 * 64];  // [buf][kv][d], XOR-swizzled image
  __shared__ u16 Vs[2 * 64 * 64];  // [buf][d][kv], XOR-swizzled image
  __shared__ u16 Ps[4 * 16 * 64];  // per-wave [q][kv]

  const int l4 = lane & 15;
  const int g = lane >> 4;
  const int kc = g * 8;
  const int swz = (l4 & 7) << 3;  // read-side swizzle (row ≡ l4 mod 8)

  const int qrow = qblk + wv * 16 + l4;
  const u16* Qp = Qh + ((size_t)h * L_SEQ + qrow) * HD;
  const bf16x8 qf0 = *(const bf16x8*)(Qp + kc);
  const bf16x8 qf1 = *(const bf16x8*)(Qp + 32 + kc);
  const bf16x8 ones = (bf16x8)(short)0x3F80;

  f32x4 oacc[4];
#pragma unroll
  for (int dt = 0; dt < 4; dt++) oacc[dt] = (f32x4)(0.0f);
  float mr = -1e30f;                   // running max for OWN q-row (q = l4)
  float lr[4] = {0.f, 0.f, 0.f, 0.f};  // denom for oacc rows (q = g*4+r)

  // staging: thread t fills LDS bytes [t*16, t*16+16) of each half-tile.
  // LDS row = t>>3, lin col16B = t&7; source col pre-swizzled (involution).
  const int srow = tid >> 3;                                    // 0..31
  const int scol = (((tid & 7) << 3) ^ ((srow & 7) << 3));      // u16 units
  const u16* KgS = Kh + ((size_t)h * L_SEQ + srow) * HD + scol; // +kb*HD/tile
  const u16* VgS = Vt + ((size_t)h * HD + srow) * L_SEQ + scol; // +kb/tile
  char* KsD = (char*)Ks + wv * 1024;  // + cur*8192 (+4096 for 2nd half)
  char* VsD = (char*)Vs + wv * 1024;

  // prologue: tile 0 -> buf0 (async; barrier drains vmcnt)
  gload_lds16(KgS, KsD);
  gload_lds16(KgS + (size_t)32 * HD, KsD + 4096);
  gload_lds16(VgS, VsD);
  gload_lds16(VgS + (size_t)32 * L_SEQ, VsD + 4096);
  __syncthreads();

  int cur = 0;
  for (int kb = 0; kb < L_SEQ; kb += 64) {
    if (kb + 64 < L_SEQ) {  // async-stage next tile into other buffer
      const int bo = (cur ^ 1) * 8192;
      gload_lds16(KgS + (size_t)(kb + 64) * HD, KsD + bo);
      gload_lds16(KgS + (size_t)(kb + 96) * HD, KsD + bo + 4096);
      gload_lds16(VgS + kb + 64, VsD + bo);
      gload_lds16(VgS + kb + 64 + (size_t)32 * L_SEQ, VsD + bo + 4096);
    }
    const u16* Kc = &Ks[cur * 4096];
    const u16* Vc = &Vs[cur * 4096];

    // QK^T swapped: s[st] = K_st * Q -> S^T (kv = 16st+4g+r, q = l4)
    f32x4 s[4];
    __builtin_amdgcn_s_setprio(1);
#pragma unroll
    for (int st = 0; st < 4; st++) {
      const u16* kp = Kc + (st * 16 + l4) * 64;
      bf16x8 ka = *(const bf16x8*)(kp + (kc ^ swz));
      bf16x8 kb2 = *(const bf16x8*)(kp + ((kc + 32) ^ swz));
      s[st] = __builtin_amdgcn_mfma_f32_16x16x32_bf16(ka, qf0, (f32x4)(0.0f), 0, 0, 0);
      s[st] = __builtin_amdgcn_mfma_f32_16x16x32_bf16(kb2, qf1, s[st], 0, 0, 0);
    }
    __builtin_amdgcn_s_setprio(0);

    // per-row max (q = l4): fused max chain + 2 cross-group shuffles
    float mx = fmaxf(fmaxf(s[0][0], s[0][1]), fmaxf(s[0][2], s[0][3]));
    mx = fmaxf(fmaxf(mx, s[1][0]), fmaxf(s[1][1], s[1][2]));
    mx = fmaxf(fmaxf(mx, s[1][3]), fmaxf(s[2][0], s[2][1]));
    mx = fmaxf(fmaxf(mx, s[2][2]), fmaxf(s[2][3], s[3][0]));
    mx = fmaxf(fmaxf(mx, s[3][1]), fmaxf(s[3][2], s[3][3]));
    mx = fmaxf(mx, __shfl_xor(mx, 16));
    mx = fmaxf(mx, __shfl_xor(mx, 32));

    // defer-max (T13, THR=8 in log2 domain: P bounded by 2^8)
    if (__any(mx > mr + 8.0f)) {
      const float nm = fmaxf(mr, mx);
      const float sclo = __builtin_amdgcn_exp2f(mr - nm);
      mr = nm;
      float scl[4];
#pragma unroll
      for (int r = 0; r < 4; r++) scl[r] = __shfl(sclo, g * 4 + r);
#pragma unroll
      for (int r = 0; r < 4; r++) lr[r] *= scl[r];
#pragma unroll
      for (int dt = 0; dt < 4; dt++)
#pragma unroll
        for (int r = 0; r < 4; r++) oacc[dt][r] *= scl[r];
    }

    // P = exp2(s - mr); packed via v_cvt_pk_bf16_f32 (RNE), 4x b64 writes
    u16* pr = &Ps[wv * 1024 + l4 * 64];
#pragma unroll
    for (int st = 0; st < 4; st++) {
      uint2 pw;
      pw.x = cvt_pk_bf16(__builtin_amdgcn_exp2f(s[st][0] - mr),
                         __builtin_amdgcn_exp2f(s[st][1] - mr));
      pw.y = cvt_pk_bf16(__builtin_amdgcn_exp2f(s[st][2] - mr),
                         __builtin_amdgcn_exp2f(s[st][3] - mr));
      *(uint2*)(pr + ((st * 16 + g * 4) ^ swz)) = pw;
    }
    // COMPILER FENCE: P-reads below consume OTHER lanes' P-writes above; they
    // don't alias per-thread, so forbid IR/MI reordering across this point.
    asm volatile("" ::: "memory");

    // PV + ones-MFMA row sums
    const u16* pp = &Ps[wv * 1024 + l4 * 64];
    bf16x8 pf0 = *(const bf16x8*)(pp + (kc ^ swz));
    bf16x8 pf1 = *(const bf16x8*)(pp + ((kc + 32) ^ swz));
    __builtin_amdgcn_s_setprio(1);
    f32x4 ls = __builtin_amdgcn_mfma_f32_16x16x32_bf16(pf0, ones, (f32x4)(0.0f), 0, 0, 0);
    ls = __builtin_amdgcn_mfma_f32_16x16x32_bf16(pf1, ones, ls, 0, 0, 0);
#pragma unroll
    for (int dt = 0; dt < 4; dt++) {
      const u16* vp = Vc + (dt * 16 + l4) * 64;
      bf16x8 vf0 = *(const bf16x8*)(vp + (kc ^ swz));
      bf16x8 vf1 = *(const bf16x8*)(vp + ((kc + 32) ^ swz));
      oacc[dt] = __builtin_amdgcn_mfma_f32_16x16x32_bf16(pf0, vf0, oacc[dt], 0, 0, 0);
      oacc[dt] = __builtin_amdgcn_mfma_f32_16x16x32_bf16(pf1, vf1, oacc[dt], 0, 0, 0);
    }
    __builtin_amdgcn_s_setprio(0);
#pragma unroll
    for (int r = 0; r < 4; r++) lr[r] += ls[r];

    __syncthreads();  // drains vmcnt (staged tile landed) + guards buf reuse
    cur ^= 1;
  }

#pragma unroll
  for (int r = 0; r < 4; r++) {
    const float inv = 1.0f / lr[r];
    const int row = qblk + wv * 16 + g * 4 + r;
#pragma unroll
    for (int dt = 0; dt < 4; dt++) {
      const int col = h * HD + dt * 16 + l4;
      O[(size_t)row * DIM + col] = f2bf(oacc[dt][r] * inv);
    }
  }
}

// ---------------- launcher ----------------
extern "C" void kernel_launch(void* const* d_in, const int* in_sizes, int n_in,
                              void* d_out, int out_size, void* d_ws, size_t ws_size,
                              hipStream_t stream) {
  const float* x = (const float*)d_in[0];
  const float* w_qkv = (const float*)d_in[1];
  const float* b_qkv = (const float*)d_in[2];
  const float* w_proj = (const float*)d_in[3];
  const float* b_proj = (const float*)d_in[4];
  const float* g_q = (const float*)d_in[5];
  const float* g_k = (const float*)d_in[6];

  char* ws = (char*)d_ws;
  u16* x_b = (u16*)(ws + 0);           // 6291456
  u16* wqkv_b = (u16*)(ws + 6291456);  // 14155776
  u16* wpj_b = (u16*)(ws + 20447232);  // 4718592
  u16* qkv = (u16*)(ws + 25165824);    // 18874368
  u16* Qh = (u16*)(ws + 44040192);     // 6291456
  u16* Kh = (u16*)(ws + 50331648);     // 6291456
  u16* Vt = (u16*)(ws + 56623104);     // 6291456
  u16* Ob = (u16*)(ws + 62914560);     // 6291456 -> total 69206016

  cast3_kernel<<<3072, 256, 0, stream>>>(x, w_qkv, w_proj, x_b);

  gemm_bt<1, 128><<<(L_SEQ / 128) * (NQKV / 128), 256, 0, stream>>>(
      x_b, wqkv_b, b_qkv, (void*)qkv, L_SEQ, NQKV, DIM);

  qkvnorm_kernel<<<dim3(L_SEQ / 64, NH), 256, 0, stream>>>(qkv, g_q, g_k, Qh, Kh, Vt);

  flash_kernel<<<dim3(L_SEQ / 64, NH), 256, 0, stream>>>(Qh, Kh, Vt, Ob);

  // d_out is float32; proj tiled 128x64 -> 384 blocks (all CUs busy)
  gemm_bt<0, 64><<<(L_SEQ / 128) * (DIM / 64), 256, 0, stream>>>(
      Ob, wpj_b, b_proj, d_out, L_SEQ, DIM, DIM);
}

// Round 24
// 145.987 us; speedup vs baseline: 1.0068x; 1.0068x over previous
//
#include <hip/hip_runtime.h>
#include <stdint.h>

#define L_SEQ 2048
#define DIM 1536
#define NH 24
#define HD 64
#define NQKV 4608

typedef unsigned short u16;
typedef __attribute__((ext_vector_type(4))) float f32x4;
typedef __attribute__((ext_vector_type(8))) short bf16x8;
typedef __attribute__((ext_vector_type(4))) u16 u16x4;
typedef __attribute__((ext_vector_type(8))) u16 u16x8;

__device__ __forceinline__ u16 f2bf(float f) {
  unsigned u = __builtin_bit_cast(unsigned, f);
  u += 0x7fffu + ((u >> 16) & 1u);
  return (u16)(u >> 16);
}
__device__ __forceinline__ float b2f(u16 u) {
  return __builtin_bit_cast(float, (unsigned)u << 16);
}
__device__ __forceinline__ unsigned cvt_pk_bf16(float lo, float hi) {
  unsigned r;
  asm("v_cvt_pk_bf16_f32 %0, %1, %2" : "=v"(r) : "v"(lo), "v"(hi));
  return r;
}

__device__ __forceinline__ void gload_lds16(const void* g, void* lds) {
  __builtin_amdgcn_global_load_lds(
      (const __attribute__((address_space(1))) unsigned int*)g,
      (__attribute__((address_space(3))) unsigned int*)lds, 16, 0, 0);
}

// ---------------- fused cast f32 -> bf16 for x, w_qkv, w_proj ----------------
__global__ __launch_bounds__(256) void cast3_kernel(const float* __restrict__ x,
                                                    const float* __restrict__ wq,
                                                    const float* __restrict__ wp,
                                                    u16* __restrict__ out) {
  const int n1 = (L_SEQ * DIM) / 4;
  const int n2 = (NQKV * DIM) / 4;
  const int n3 = (DIM * DIM) / 4;
  const int tot = n1 + n2 + n3;
  for (int i = blockIdx.x * 256 + threadIdx.x; i < tot; i += gridDim.x * 256) {
    const f32x4* src;
    int j;
    if (i < n1) {
      src = (const f32x4*)x;
      j = i;
    } else if (i < n1 + n2) {
      src = (const f32x4*)wq;
      j = i - n1;
    } else {
      src = (const f32x4*)wp;
      j = i - n1 - n2;
    }
    f32x4 v = src[j];
    u16x4 o;
    o.x = f2bf(v.x);
    o.y = f2bf(v.y);
    o.z = f2bf(v.z);
    o.w = f2bf(v.w);
    ((u16x4*)out)[i] = o;
  }
}

// ---------------- GEMM: C[M][N] = A[M][K] * B[N][K]^T + bias ----------------
// 128 x BN tile (BN=128 or 64), BK=32, 4 waves, 16x16x32 MFMA, global_load_lds,
// 2-phase dbuf, XCD-bijective swizzle. Wave = 64 rows x BN/2 cols.
template <int WRITE_BF16, int BN>
__global__ __launch_bounds__(256) void gemm_bt(const u16* __restrict__ A,
                                               const u16* __restrict__ B,
                                               const float* __restrict__ bias,
                                               void* __restrict__ Cout,
                                               int M, int N, int K) {
  constexpr int NT = BN / 64 * 2;  // acc col-frags per wave: 4 (BN=128) or 2 (BN=64)
  __shared__ u16 As[2][128 * 32];
  __shared__ u16 Bs[2][BN * 32];
  const int mb = M >> 7;
  const int f = (int)blockIdx.x;
  const int f2 = (f & 7) * ((int)gridDim.x >> 3) + (f >> 3);
  const int bx = f2 / mb;  // col tile (slow within an XCD chunk)
  const int by = f2 % mb;  // row tile (fast)
  const int tid = threadIdx.x;
  const int lane = tid & 63;
  const int l4 = lane & 15;
  const int wv = tid >> 6;
  const int wr = wv >> 1, wc = wv & 1;

  f32x4 acc[4][NT];
#pragma unroll
  for (int i = 0; i < 4; i++)
#pragma unroll
    for (int j = 0; j < NT; j++) acc[i][j] = (f32x4)(0.0f);

  const int e0 = tid * 8;
  const int r0 = e0 >> 5, c0 = e0 & 31;
  const u16* Ag0 = A + (size_t)(by * 128 + r0) * K + c0;
  const u16* Ag1 = A + (size_t)(by * 128 + r0 + 64) * K + c0;
  const u16* Bg0 = B + (size_t)(bx * BN + r0) * K + c0;
  const u16* Bg1 = B + (size_t)(bx * BN + r0 + 64) * K + c0;  // used only BN=128
  const int kc = (lane >> 4) * 8;
  const int wb = wv * 1024;

  gload_lds16(Ag0, (char*)As[0] + wb);
  gload_lds16(Ag1, (char*)As[0] + wb + 4096);
  gload_lds16(Bg0, (char*)Bs[0] + wb);
  if (BN == 128) gload_lds16(Bg1, (char*)Bs[0] + wb + 4096);
  __syncthreads();

  int cur = 0;
  for (int k0 = 0; k0 < K; k0 += 32) {
    const int nxt = cur ^ 1;
    if (k0 + 32 < K) {
      gload_lds16(Ag0 + k0 + 32, (char*)As[nxt] + wb);
      gload_lds16(Ag1 + k0 + 32, (char*)As[nxt] + wb + 4096);
      gload_lds16(Bg0 + k0 + 32, (char*)Bs[nxt] + wb);
      if (BN == 128) gload_lds16(Bg1 + k0 + 32, (char*)Bs[nxt] + wb + 4096);
    }
    const u16* Asc = As[cur];
    const u16* Bsc = Bs[cur];
    bf16x8 af[4], bfr[NT];
#pragma unroll
    for (int mt = 0; mt < 4; mt++)
      af[mt] = *(const bf16x8*)&Asc[(wr * 64 + mt * 16 + l4) * 32 + kc];
#pragma unroll
    for (int nt = 0; nt < NT; nt++)
      bfr[nt] = *(const bf16x8*)&Bsc[(wc * (BN / 2) + nt * 16 + l4) * 32 + kc];
#pragma unroll
    for (int mt = 0; mt < 4; mt++)
#pragma unroll
      for (int nt = 0; nt < NT; nt++)
        acc[mt][nt] = __builtin_amdgcn_mfma_f32_16x16x32_bf16(af[mt], bfr[nt],
                                                              acc[mt][nt], 0, 0, 0);
    __syncthreads();
    cur = nxt;
  }

  // C/D layout: col = l4, row = (lane>>4)*4 + reg
  const int colb = bx * BN + wc * (BN / 2) + l4;
  const int rowb = by * 128 + wr * 64 + ((lane >> 4) << 2);
#pragma unroll
  for (int nt = 0; nt < NT; nt++) {
    const int col = colb + nt * 16;
    const float bv = bias[col];
#pragma unroll
    for (int mt = 0; mt < 4; mt++) {
#pragma unroll
      for (int r = 0; r < 4; r++) {
        const int row = rowb + mt * 16 + r;
        float v = acc[mt][nt][r] + bv;
        if (WRITE_BF16)
          ((u16*)Cout)[(size_t)row * N + col] = f2bf(v);
        else
          ((float*)Cout)[(size_t)row * N + col] = v;
      }
    }
  }
}

// ---------------- QK-RMSNorm + layout rearrange (bf16 qkv input) ------------
__global__ __launch_bounds__(256) void qkvnorm_kernel(const u16* __restrict__ qkv,
                                                      const float* __restrict__ gq,
                                                      const float* __restrict__ gk,
                                                      u16* __restrict__ Qh,
                                                      u16* __restrict__ Kh,
                                                      u16* __restrict__ Vt) {
  const int h = blockIdx.y;
  const int lblk = blockIdx.x * 64;
  const int tid = threadIdx.x;
  const int lane = tid & 63, wv = tid >> 6;
  __shared__ u16 vt[64][64];
  const float gqv = gq[lane] * 0.125f * 1.44269504088896f;  // 1/sqrt(HD) * log2(e)
  const float gkv = gk[lane];
#pragma unroll 1
  for (int i = 0; i < 16; i++) {
    const int l = lblk + wv * 16 + i;
    const size_t base = (size_t)l * NQKV + h * HD + lane;
    const float q = b2f(qkv[base]);
    const float k = b2f(qkv[base + DIM]);
    float sq = q * q, sk = k * k;
#pragma unroll
    for (int m = 32; m; m >>= 1) {
      sq += __shfl_xor(sq, m);
      sk += __shfl_xor(sk, m);
    }
    const float rq = rsqrtf(sq * (1.0f / 64.0f) + 1e-6f);
    const float rk = rsqrtf(sk * (1.0f / 64.0f) + 1e-6f);
    const size_t ho = ((size_t)h * L_SEQ + l) * HD + lane;
    Qh[ho] = f2bf(q * rq * gqv);
    Kh[ho] = f2bf(k * rk * gkv);
    vt[wv * 16 + i][lane] = qkv[base + 2 * DIM];
  }
  __syncthreads();
  const int d = tid >> 2;
  const int cb = (tid & 3) * 16;
  u16* dst = Vt + ((size_t)h * HD + d) * L_SEQ + lblk + cb;
#pragma unroll
  for (int j0 = 0; j0 < 4; j0++) {
    u16x4 o;
    o.x = vt[cb + j0 * 4 + 0][d];
    o.y = vt[cb + j0 * 4 + 1][d];
    o.z = vt[cb + j0 * 4 + 2][d];
    o.w = vt[cb + j0 * 4 + 3][d];
    *(u16x4*)(dst + j0 * 4) = o;
  }
}

// ---------------- MFMA flash: R18 structure + compiler memory fence ----------
// K/V double-buffered (reg-staged), 1 barrier/tile; MAX-SHIFT online softmax
// (fixed-shift variants fail 3/3 across structures — permanently closed).
// The P LDS write->read pair does NOT alias per-thread (reads consume other
// lanes' writes): the asm-"memory" fence forbids compiler reordering.
__global__ __launch_bounds__(256) void flash_kernel(const u16* __restrict__ Qh,
                                                    const u16* __restrict__ Kh,
                                                    const u16* __restrict__ Vt,
                                                    u16* __restrict__ O) {
  const int f = (int)blockIdx.y * (L_SEQ / 64) + (int)blockIdx.x;  // 0..767
  const int f2 = (f & 7) * 96 + (f >> 3);  // bijective (768 % 8 == 0)
  const int h = f2 >> 5;
  const int qblk = (f2 & 31) * 64;
  const int tid = threadIdx.x;
  const int lane = tid & 63, wv = tid >> 6;
  __shared__ u16 Ks[2 * 64 * 64];  // [buf][kv][d]
  __shared__ u16 Vs[2 * 64 * 64];  // [buf][d][kv]
  __shared__ u16 Ps[4 * 16 * 64];  // per-wave [q][kv]

  const int l4 = lane & 15;
  const int g = lane >> 4;
  const int kc = g * 8;
  const int swz = (l4 & 7) << 3;  // row-determined swizzle (row ≡ l4 mod 8)

  const int qrow = qblk + wv * 16 + l4;
  const u16* Qp = Qh + ((size_t)h * L_SEQ + qrow) * HD;
  const bf16x8 qf0 = *(const bf16x8*)(Qp + kc);
  const bf16x8 qf1 = *(const bf16x8*)(Qp + 32 + kc);
  const bf16x8 ones = (bf16x8)(short)0x3F80;

  f32x4 oacc[4];
#pragma unroll
  for (int dt = 0; dt < 4; dt++) oacc[dt] = (f32x4)(0.0f);
  float mr = -1e30f;                   // running max for OWN q-row (q = l4)
  float lr[4] = {0.f, 0.f, 0.f, 0.f};  // denom for oacc rows (q = g*4+r)

  const int krow = tid >> 3;
  const int kcol = (tid & 7) * 8;
  const u16* Kg = Kh + (size_t)h * L_SEQ * HD + (size_t)krow * HD + kcol;
  u16* KsW0 = &Ks[krow * 64 + (kcol ^ ((krow & 7) << 3))];
  u16* KsW1 = KsW0 + 32 * 64;
  const int vd = tid >> 2;
  const int vcol = (tid & 3) * 16;
  const u16* Vg = Vt + ((size_t)h * HD + vd) * L_SEQ;
  u16* VsW0 = &Vs[vd * 64 + (vcol ^ ((vd & 7) << 3))];
  u16* VsW1 = &Vs[vd * 64 + ((vcol + 8) ^ ((vd & 7) << 3))];

  // prologue: tile 0 -> buf0; tile 1 -> regs
  bf16x8 kr0 = *(const bf16x8*)(Kg);
  bf16x8 kr1 = *(const bf16x8*)(Kg + 32 * HD);
  bf16x8 vr0 = *(const bf16x8*)(Vg + vcol);
  bf16x8 vr1 = *(const bf16x8*)(Vg + vcol + 8);
  *(bf16x8*)KsW0 = kr0;
  *(bf16x8*)KsW1 = kr1;
  *(bf16x8*)VsW0 = vr0;
  *(bf16x8*)VsW1 = vr1;
  kr0 = *(const bf16x8*)(Kg + (size_t)64 * HD);
  kr1 = *(const bf16x8*)(Kg + (size_t)96 * HD);
  vr0 = *(const bf16x8*)(Vg + 64 + vcol);
  vr1 = *(const bf16x8*)(Vg + 64 + vcol + 8);
  __syncthreads();

  int cur = 0;
  for (int kb = 0; kb < L_SEQ; kb += 64) {
    if (kb + 64 < L_SEQ) {
      const int bo = (cur ^ 1) * 4096;  // next buffer
      *(bf16x8*)(KsW0 + bo) = kr0;
      *(bf16x8*)(KsW1 + bo) = kr1;
      *(bf16x8*)(VsW0 + bo) = vr0;
      *(bf16x8*)(VsW1 + bo) = vr1;
      if (kb + 128 < L_SEQ) {  // T14, depth 2
        kr0 = *(const bf16x8*)(Kg + (size_t)(kb + 128) * HD);
        kr1 = *(const bf16x8*)(Kg + (size_t)(kb + 160) * HD);
        vr0 = *(const bf16x8*)(Vg + kb + 128 + vcol);
        vr1 = *(const bf16x8*)(Vg + kb + 128 + vcol + 8);
      }
    }
    const u16* Kc = &Ks[cur * 4096];
    const u16* Vc = &Vs[cur * 4096];

    // QK^T swapped: s[st] = K_st * Q -> S^T (kv = 16st+4g+r, q = l4)
    f32x4 s[4];
    __builtin_amdgcn_s_setprio(1);
#pragma unroll
    for (int st = 0; st < 4; st++) {
      const u16* kp = Kc + (st * 16 + l4) * 64;
      bf16x8 ka = *(const bf16x8*)(kp + (kc ^ swz));
      bf16x8 kb2 = *(const bf16x8*)(kp + ((kc + 32) ^ swz));
      s[st] = __builtin_amdgcn_mfma_f32_16x16x32_bf16(ka, qf0, (f32x4)(0.0f), 0, 0, 0);
      s[st] = __builtin_amdgcn_mfma_f32_16x16x32_bf16(kb2, qf1, s[st], 0, 0, 0);
    }
    __builtin_amdgcn_s_setprio(0);

    // per-row max (q = l4): fused max chain + 2 cross-group shuffles
    float mx = fmaxf(fmaxf(s[0][0], s[0][1]), fmaxf(s[0][2], s[0][3]));
    mx = fmaxf(fmaxf(mx, s[1][0]), fmaxf(s[1][1], s[1][2]));
    mx = fmaxf(fmaxf(mx, s[1][3]), fmaxf(s[2][0], s[2][1]));
    mx = fmaxf(fmaxf(mx, s[2][2]), fmaxf(s[2][3], s[3][0]));
    mx = fmaxf(fmaxf(mx, s[3][1]), fmaxf(s[3][2], s[3][3]));
    mx = fmaxf(mx, __shfl_xor(mx, 16));
    mx = fmaxf(mx, __shfl_xor(mx, 32));

    // defer-max (T13, THR=8 in log2 domain: P bounded by 2^8)
    if (__any(mx > mr + 8.0f)) {
      const float nm = fmaxf(mr, mx);
      const float sclo = __builtin_amdgcn_exp2f(mr - nm);
      mr = nm;
      float scl[4];
#pragma unroll
      for (int r = 0; r < 4; r++) scl[r] = __shfl(sclo, g * 4 + r);
#pragma unroll
      for (int r = 0; r < 4; r++) lr[r] *= scl[r];
#pragma unroll
      for (int dt = 0; dt < 4; dt++)
#pragma unroll
        for (int r = 0; r < 4; r++) oacc[dt][r] *= scl[r];
    }

    // P = exp2(s - mr); packed via v_cvt_pk_bf16_f32 (RNE), 4x b64 writes
    u16* pr = &Ps[wv * 1024 + l4 * 64];
#pragma unroll
    for (int st = 0; st < 4; st++) {
      uint2 pw;
      pw.x = cvt_pk_bf16(__builtin_amdgcn_exp2f(s[st][0] - mr),
                         __builtin_amdgcn_exp2f(s[st][1] - mr));
      pw.y = cvt_pk_bf16(__builtin_amdgcn_exp2f(s[st][2] - mr),
                         __builtin_amdgcn_exp2f(s[st][3] - mr));
      *(uint2*)(pr + ((st * 16 + g * 4) ^ swz)) = pw;
    }
    // COMPILER FENCE: P-reads below consume OTHER lanes' P-writes above; they
    // don't alias per-thread, so without this the compiler may reorder them.
    asm volatile("" ::: "memory");

    // PV + ones-MFMA row sums
    const u16* pp = &Ps[wv * 1024 + l4 * 64];
    bf16x8 pf0 = *(const bf16x8*)(pp + (kc ^ swz));
    bf16x8 pf1 = *(const bf16x8*)(pp + ((kc + 32) ^ swz));
    __builtin_amdgcn_s_setprio(1);
    f32x4 ls = __builtin_amdgcn_mfma_f32_16x16x32_bf16(pf0, ones, (f32x4)(0.0f), 0, 0, 0);
    ls = __builtin_amdgcn_mfma_f32_16x16x32_bf16(pf1, ones, ls, 0, 0, 0);
#pragma unroll
    for (int dt = 0; dt < 4; dt++) {
      const u16* vp = Vc + (dt * 16 + l4) * 64;
      bf16x8 vf0 = *(const bf16x8*)(vp + (kc ^ swz));
      bf16x8 vf1 = *(const bf16x8*)(vp + ((kc + 32) ^ swz));
      oacc[dt] = __builtin_amdgcn_mfma_f32_16x16x32_bf16(pf0, vf0, oacc[dt], 0, 0, 0);
      oacc[dt] = __builtin_amdgcn_mfma_f32_16x16x32_bf16(pf1, vf1, oacc[dt], 0, 0, 0);
    }
    __builtin_amdgcn_s_setprio(0);
#pragma unroll
    for (int r = 0; r < 4; r++) lr[r] += ls[r];

    __syncthreads();  // single barrier per tile
    cur ^= 1;
  }

#pragma unroll
  for (int r = 0; r < 4; r++) {
    const float inv = 1.0f / lr[r];
    const int row = qblk + wv * 16 + g * 4 + r;
#pragma unroll
    for (int dt = 0; dt < 4; dt++) {
      const int col = h * HD + dt * 16 + l4;
      O[(size_t)row * DIM + col] = f2bf(oacc[dt][r] * inv);
    }
  }
}

// ---------------- launcher ----------------
extern "C" void kernel_launch(void* const* d_in, const int* in_sizes, int n_in,
                              void* d_out, int out_size, void* d_ws, size_t ws_size,
                              hipStream_t stream) {
  const float* x = (const float*)d_in[0];
  const float* w_qkv = (const float*)d_in[1];
  const float* b_qkv = (const float*)d_in[2];
  const float* w_proj = (const float*)d_in[3];
  const float* b_proj = (const float*)d_in[4];
  const float* g_q = (const float*)d_in[5];
  const float* g_k = (const float*)d_in[6];

  char* ws = (char*)d_ws;
  u16* x_b = (u16*)(ws + 0);           // 6291456
  u16* wqkv_b = (u16*)(ws + 6291456);  // 14155776
  u16* wpj_b = (u16*)(ws + 20447232);  // 4718592
  u16* qkv = (u16*)(ws + 25165824);    // 18874368
  u16* Qh = (u16*)(ws + 44040192);     // 6291456
  u16* Kh = (u16*)(ws + 50331648);     // 6291456
  u16* Vt = (u16*)(ws + 56623104);     // 6291456
  u16* Ob = (u16*)(ws + 62914560);     // 6291456 -> total 69206016

  cast3_kernel<<<3072, 256, 0, stream>>>(x, w_qkv, w_proj, x_b);

  gemm_bt<1, 128><<<(L_SEQ / 128) * (NQKV / 128), 256, 0, stream>>>(
      x_b, wqkv_b, b_qkv, (void*)qkv, L_SEQ, NQKV, DIM);

  qkvnorm_kernel<<<dim3(L_SEQ / 64, NH), 256, 0, stream>>>(qkv, g_q, g_k, Qh, Kh, Vt);

  flash_kernel<<<dim3(L_SEQ / 64, NH), 256, 0, stream>>>(Qh, Kh, Vt, Ob);

  // d_out is float32; proj tiled 128x64 -> 384 blocks (all CUs busy)
  gemm_bt<0, 64><<<(L_SEQ / 128) * (DIM / 64), 256, 0, stream>>>(
      Ob, wpj_b, b_proj, d_out, L_SEQ, DIM, DIM);
}